// Round 2
// baseline (838.555 us; speedup 1.0000x reference)
//
#include <hip/hip_runtime.h>
#include <hip/hip_bf16.h>

typedef unsigned short u16;
typedef unsigned int u32;
typedef __bf16 bf16x8 __attribute__((ext_vector_type(8)));
typedef float f32x4 __attribute__((ext_vector_type(4)));

__device__ __forceinline__ float bf2f(u16 h) { return __uint_as_float(((u32)h) << 16); }
__device__ __forceinline__ u16 f2bf(float f) {
    u32 u = __float_as_uint(f);
    u32 r = u + 0x7FFFu + ((u >> 16) & 1u);   // round-to-nearest-even
    return (u16)(r >> 16);
}
// monotone float->uint map for atomic max; key 0 is reserved "empty" (decodes from no writes -> 0.0)
__device__ __forceinline__ u32 fkey(float f) {
    u32 u = __float_as_uint(f);
    return ((int)u < 0) ? ~u : (u | 0x80000000u);
}
__device__ __forceinline__ float fdec(u32 k) {
    u32 u = (k & 0x80000000u) ? (k & 0x7FFFFFFFu) : ~k;
    return __uint_as_float(u);
}
__device__ __forceinline__ void unpack8(const u16* p, float* b) {
    uint4 v = *(const uint4*)p;
    b[0] = bf2f((u16)(v.x & 0xFFFF)); b[1] = bf2f((u16)(v.x >> 16));
    b[2] = bf2f((u16)(v.y & 0xFFFF)); b[3] = bf2f((u16)(v.y >> 16));
    b[4] = bf2f((u16)(v.z & 0xFFFF)); b[5] = bf2f((u16)(v.z >> 16));
    b[6] = bf2f((u16)(v.w & 0xFFFF)); b[7] = bf2f((u16)(v.w >> 16));
}
template<int BF16>
__device__ __forceinline__ float LD(const void* p, long i) {
    if constexpr (BF16) return bf2f(((const u16*)p)[i]);
    else return ((const float*)p)[i];
}

// -------- detector: flags[0]=1 if floats are bf16; flags[1]=1 if edge_index is int64 --------
__global__ void k_detect(const u32* __restrict__ x, const u32* __restrict__ ei, u32* __restrict__ flags) {
    if (threadIdx.x == 0 && blockIdx.x == 0) {
        int c = 0;
        for (int i = 0; i < 256; i++) {
            u32 e = (x[i] >> 7) & 0xFF;
            if (e >= 96 && e <= 160) c++;
        }
        flags[0] = (c >= 192) ? 1u : 0u;
        int z = 0;
        for (int i = 0; i < 64; i++) if (ei[2 * i + 1] == 0u) z++;
        flags[1] = (z >= 48) ? 1u : 0u;
    }
}

__global__ void k_init(u32* __restrict__ p, int n) {
    for (int i = blockIdx.x * blockDim.x + threadIdx.x; i < n; i += gridDim.x * blockDim.x)
        p[i] = 0u;
}

// -------- prep: transposed/padded bf16 weights.  w0t[c][kp] (128x128, kp<96 -> w0src row kp+koff),
// w1t[c][k] (96x128, pitch 128).  koff=3 for f-MLP (rel rows handled separately), 0 for g-MLP. --------
__global__ void k_prep(const void* __restrict__ w0src, const void* __restrict__ w1src,
                       u16* __restrict__ w0t, u16* __restrict__ w1t,
                       const u32* __restrict__ flags, int koff) {
    int bf = (int)flags[0];
    int tid = blockIdx.x * blockDim.x + threadIdx.x;
    int stride = gridDim.x * blockDim.x;
    for (int i = tid; i < 128 * 128; i += stride) {
        int c = i >> 7, kp = i & 127;
        float v = 0.f;
        if (kp < 96) {
            int k = kp + koff;
            v = bf ? bf2f(((const u16*)w0src)[k * 128 + c]) : ((const float*)w0src)[k * 128 + c];
        }
        w0t[(long)c * 128 + kp] = f2bf(v);
    }
    for (int i = tid; i < 96 * 128; i += stride) {
        int c = i >> 7, k = i & 127;
        float v = bf ? bf2f(((const u16*)w1src)[k * 96 + c]) : ((const float*)w1src)[k * 96 + c];
        w1t[(long)c * 128 + k] = f2bf(v);
    }
}

// -------- counting sort of edges by dst: hist -> scan -> scatter --------
__global__ void k_hist(const u32* __restrict__ ei, u32* __restrict__ hist,
                       const u32* __restrict__ flags, int nE, int N) {
    u32 i64f = flags[1];
    for (long e = blockIdx.x * blockDim.x + threadIdx.x; e < nE; e += (long)gridDim.x * blockDim.x) {
        int dst = i64f ? (int)ei[2 * ((long)nE + e)] : (int)ei[(long)nE + e];
        dst = min(max(dst, 0), N - 1);
        atomicAdd(&hist[dst], 1u);
    }
}

__global__ void k_scan(u32* __restrict__ hist, int n) {   // 1 block, 256 threads, in-place exclusive scan
    __shared__ u32 sums[256];
    __shared__ u32 offs[256];
    int tid = threadIdx.x;
    int chunk = (n + 255) / 256;
    int lo = tid * chunk, hi = min(lo + chunk, n);
    u32 s = 0;
    for (int i = lo; i < hi; i++) s += hist[i];
    sums[tid] = s;
    __syncthreads();
    if (tid == 0) {
        u32 r = 0;
        for (int i = 0; i < 256; i++) { offs[i] = r; r += sums[i]; }
    }
    __syncthreads();
    u32 r = offs[tid];
    for (int i = lo; i < hi; i++) { u32 v = hist[i]; hist[i] = r; r += v; }
}

__global__ void k_scatter(const u32* __restrict__ ei, u32* __restrict__ cur,
                          u32* __restrict__ ssrc, u32* __restrict__ sdst,
                          const u32* __restrict__ flags, int nE, int N) {
    u32 i64f = flags[1];
    for (long e = blockIdx.x * blockDim.x + threadIdx.x; e < nE; e += (long)gridDim.x * blockDim.x) {
        int src, dst;
        if (i64f) { src = (int)ei[2 * e]; dst = (int)ei[2 * ((long)nE + e)]; }
        else      { src = (int)ei[e];     dst = (int)ei[(long)nE + e]; }
        src = min(max(src, 0), N - 1);
        dst = min(max(dst, 0), N - 1);
        u32 p = atomicAdd(&cur[dst], 1u);
        ssrc[p] = (u32)src;
        sdst[p] = (u32)dst;
    }
}

// -------- K1: delta = mlp_h(x)  (96 -> 64 relu -> 3), f32 out --------
template<int BF16>
__global__ void k_delta(const void* __restrict__ x,
                        const void* __restrict__ hw0, const void* __restrict__ hb0,
                        const void* __restrict__ hw1, const void* __restrict__ hb1,
                        float* __restrict__ delta, const u32* __restrict__ flags, int N)
{
    if (flags[0] != (u32)BF16) return;
    __shared__ float w0[96 * 64];
    __shared__ float b0[64];
    __shared__ float w1[64 * 3];
    __shared__ float b1[3];
    int tid = threadIdx.x;
    for (int i = tid; i < 96 * 64; i += 256) w0[i] = LD<BF16>(hw0, i);
    if (tid < 64) b0[tid] = LD<BF16>(hb0, tid);
    if (tid < 64 * 3) w1[tid] = LD<BF16>(hw1, tid);
    if (tid < 3) b1[tid] = LD<BF16>(hb1, tid);
    __syncthreads();
    int n = blockIdx.x * 256 + tid;
    if (n >= N) return;
    float acc[64];
#pragma unroll
    for (int j = 0; j < 64; j++) acc[j] = b0[j];
    if constexpr (BF16) {
        const u32* xr = (const u32*)x + (long)n * 48;
        for (int kk = 0; kk < 48; kk++) {
            u32 p = xr[kk];
            float a0 = bf2f((u16)(p & 0xFFFF));
            float a1 = bf2f((u16)(p >> 16));
            const float* wr0 = &w0[(2 * kk) * 64];
            const float* wr1 = &w0[(2 * kk + 1) * 64];
#pragma unroll
            for (int j = 0; j < 64; j++) acc[j] += a0 * wr0[j] + a1 * wr1[j];
        }
    } else {
        const float* xr = (const float*)x + (long)n * 96;
        for (int k = 0; k < 96; k++) {
            float a0 = xr[k];
            const float* wr = &w0[k * 64];
#pragma unroll
            for (int j = 0; j < 64; j++) acc[j] += a0 * wr[j];
        }
    }
    float d0 = b1[0], d1 = b1[1], d2 = b1[2];
#pragma unroll
    for (int j = 0; j < 64; j++) {
        float h = fmaxf(acc[j], 0.f);
        d0 += h * w1[j * 3 + 0];
        d1 += h * w1[j * 3 + 1];
        d2 += h * w1[j * 3 + 2];
    }
    delta[(long)n * 3 + 0] = d0; delta[(long)n * 3 + 1] = d1; delta[(long)n * 3 + 2] = d2;
}

// -------- K2: MFMA edge MLP over dst-sorted edges + run-reduced segment max --------
// 64 edges/tile, 4 waves; each wave owns 16 edge-rows (M=16) and all N-tiles.
// Depth-2 pipeline: indices for tile t+2g, gathers (in regs) for tile t+g, LDS holds tile t.
// arena[0..16K):  ein  [64][128] bf16, swizzled (byte ^= (row&7)<<4), only k'=0..95 (= x feats) used
// arena[16K..32K): h   [64][128] bf16, same swizzle
// arena[0..32K):  out  [64][128] f32 via wave-local outOff mapping (overlays ein+h after GEMM2)
#define EB 64
__device__ __forceinline__ int outOff(int row, int col) {
    int j = row & 15, w2 = row >> 4;
    int base = (j < 8) ? (w2 * 4096 + j * 512) : (16384 + w2 * 4096 + (j - 8) * 512);
    return base + ((col ^ (((row >> 2) & 3) << 4)) << 2);
}

template<int BF16>
__global__ __launch_bounds__(256)
void k_edge(const void* __restrict__ x, const void* __restrict__ pos,
            const u32* __restrict__ ssrc, const u32* __restrict__ sdst,
            const float* __restrict__ delta,
            const u16* __restrict__ w0t, const u16* __restrict__ w1t,
            const void* __restrict__ fw0, const void* __restrict__ fb0, const void* __restrict__ fb1,
            const u32* __restrict__ flags, u32* __restrict__ aggKey, int nE, int N)
{
    if (flags[0] != (u32)BF16) return;
    __shared__ __align__(16) char arena[32768];
    __shared__ float relS[64][4];
    __shared__ int dstS[64];
    __shared__ float b0s[128];
    __shared__ float b1s[96];
    __shared__ float w0rS[3 * 128];
    int tid = threadIdx.x;
    if (tid < 128) b0s[tid] = LD<BF16>(fb0, tid);
    if (tid < 96)  b1s[tid] = LD<BF16>(fb1, tid);
    for (int i = tid; i < 384; i += 256) w0rS[i] = LD<BF16>(fw0, i);   // fw0 rows 0..2 (rel part), f32 in LDS
    __syncthreads();

    const int lane = tid & 63;
    const int wid  = tid >> 6;
    const int mrow0 = wid * 16;
    const int arow = mrow0 + (lane & 15);
    const int kgrp = lane >> 4;          // 0..3
    const int srow = tid >> 2;           // staging row 0..63 (wave-local: rows 16w..16w+15)
    const int q = tid & 3;
    const int ssw = (srow & 7) << 4;

    float b0v[8];
#pragma unroll
    for (int nt = 0; nt < 8; nt++) b0v[nt] = b0s[nt * 16 + (lane & 15)];
    const int rcol = tid % 96;
    const float b1c = (tid < 192) ? b1s[rcol] : 0.f;

    // ---- prefetch state ----
    uint4 pfx[4];                  // BF16 gather regs (q<3)
    float4 pfxf[8];                // f32 gather regs (q<3)
    u32 pfps[3], pfpd[3];          // bf16 pos bits (q==3)
    float pfpsf[3], pfpdf[3];      // f32 pos (q==3)
    float pfdl[3];
    int   pfdst = 0;
    u32 nsrc = 0u, ndst = 0u;      // indices one stage further ahead

    auto issueGathers = [&](u32 src, u32 dst) {
        if (q == 3) {
            pfdst = (int)dst;
            if constexpr (BF16) {
                const u16* pp = (const u16*)pos;
#pragma unroll
                for (int c = 0; c < 3; c++) {
                    pfps[c] = pp[(size_t)src * 3 + c];
                    pfpd[c] = pp[(size_t)dst * 3 + c];
                }
            } else {
                const float* pp = (const float*)pos;
#pragma unroll
                for (int c = 0; c < 3; c++) {
                    pfpsf[c] = pp[(size_t)src * 3 + c];
                    pfpdf[c] = pp[(size_t)dst * 3 + c];
                }
            }
#pragma unroll
            for (int c = 0; c < 3; c++) pfdl[c] = delta[(size_t)dst * 3 + c];
        } else {
            if constexpr (BF16) {
                const uint4* xp = (const uint4*)((const u16*)x + (size_t)src * 96);
#pragma unroll
                for (int j = 0; j < 4; j++) pfx[j] = xp[q * 4 + j];
            } else {
                const float4* xp = (const float4*)((const float*)x + (size_t)src * 96);
#pragma unroll
                for (int j = 0; j < 8; j++) pfxf[j] = xp[q * 8 + j];
            }
        }
    };
    auto writeStage = [&]() {
        if (q == 3) {
            dstS[srow] = pfdst;
            if constexpr (BF16) {
#pragma unroll
                for (int c = 0; c < 3; c++)
                    relS[srow][c] = bf2f((u16)pfps[c]) - bf2f((u16)pfpd[c]) + pfdl[c];
            } else {
#pragma unroll
                for (int c = 0; c < 3; c++)
                    relS[srow][c] = pfpsf[c] - pfpdf[c] + pfdl[c];
            }
        } else {
            if constexpr (BF16) {
#pragma unroll
                for (int j = 0; j < 4; j++) {
                    int c = q * 4 + j;
                    *(uint4*)(arena + srow * 256 + ((c * 16) ^ ssw)) = pfx[j];
                }
            } else {
#pragma unroll
                for (int j = 0; j < 4; j++) {
                    int c = q * 4 + j;
                    float4 v0 = pfxf[2 * j], v1 = pfxf[2 * j + 1];
                    u32 o0 = (u32)f2bf(v0.x) | ((u32)f2bf(v0.y) << 16);
                    u32 o1 = (u32)f2bf(v0.z) | ((u32)f2bf(v0.w) << 16);
                    u32 o2 = (u32)f2bf(v1.x) | ((u32)f2bf(v1.y) << 16);
                    u32 o3 = (u32)f2bf(v1.z) | ((u32)f2bf(v1.w) << 16);
                    *(uint4*)(arena + srow * 256 + ((c * 16) ^ ssw)) = make_uint4(o0, o1, o2, o3);
                }
            }
        }
    };

    const int g = (int)gridDim.x;
    int ntile = nE / EB;   // 12500 exact
    int t = blockIdx.x;
    if (t < ntile) {
        long E = (long)t * EB + srow;
        u32 s0 = ssrc[E], d0 = sdst[E];
        issueGathers(s0, d0);
        int tn = t + g;
        if (tn < ntile) {
            long En = (long)tn * EB + srow;
            nsrc = ssrc[En]; ndst = sdst[En];
        }
    }
    for (; t < ntile; t += g) {
        asm volatile("" ::: "memory");   // block LICM from hoisting loop-invariant B-fragment loads
        writeStage();                    // regs (tile t) -> LDS
        __syncthreads();
        {   // issue gathers for t+g (indices already resident), then indices for t+2g
            int tn = t + g;
            if (tn < ntile) {
                issueGathers(nsrc, ndst);
                int tn2 = tn + g;
                if (tn2 < ntile) {
                    long E2 = (long)tn2 * EB + srow;
                    nsrc = ssrc[E2]; ndst = sdst[E2];
                }
            }
        }
        // ---- GEMM1: h = relu(ein @ W0 + b0), K=96 MFMA + rank-3 rel init in f32 ----
        float rl[4][3];
#pragma unroll
        for (int r = 0; r < 4; r++) {
            int row = mrow0 + kgrp * 4 + r;
            rl[r][0] = relS[row][0]; rl[r][1] = relS[row][1]; rl[r][2] = relS[row][2];
        }
        f32x4 acc[8];
#pragma unroll
        for (int nt = 0; nt < 8; nt++) {
            int col = nt * 16 + (lane & 15);
            float wr0 = w0rS[col], wr1 = w0rS[128 + col], wr2 = w0rS[256 + col];
#pragma unroll
            for (int r = 0; r < 4; r++)
                acc[nt][r] = rl[r][0] * wr0 + rl[r][1] * wr1 + rl[r][2] * wr2;
        }
        int sw = (arow & 7) << 4;
        bf16x8 a0 = *(const bf16x8*)(arena + arow * 256 + ((0   + kgrp * 16) ^ sw));
        bf16x8 a1 = *(const bf16x8*)(arena + arow * 256 + ((64  + kgrp * 16) ^ sw));
        bf16x8 a2 = *(const bf16x8*)(arena + arow * 256 + ((128 + kgrp * 16) ^ sw));
#pragma unroll
        for (int nt = 0; nt < 8; nt++) {
            const u16* wp = w0t + (long)(nt * 16 + (lane & 15)) * 128 + kgrp * 8;
            acc[nt] = __builtin_amdgcn_mfma_f32_16x16x32_bf16(a0, *(const bf16x8*)(wp),      acc[nt], 0, 0, 0);
            acc[nt] = __builtin_amdgcn_mfma_f32_16x16x32_bf16(a1, *(const bf16x8*)(wp + 32), acc[nt], 0, 0, 0);
            acc[nt] = __builtin_amdgcn_mfma_f32_16x16x32_bf16(a2, *(const bf16x8*)(wp + 64), acc[nt], 0, 0, 0);
        }
        // h -> bf16 -> LDS (wave-local rows; in-order DS per wave, no barrier needed)
#pragma unroll
        for (int nt = 0; nt < 8; nt++) {
            int col = nt * 16 + (lane & 15);
#pragma unroll
            for (int r = 0; r < 4; r++) {
                int row = mrow0 + kgrp * 4 + r;
                float hv = fmaxf(acc[nt][r] + b0v[nt], 0.f);
                *(u16*)(arena + 16384 + row * 256 + ((col * 2) ^ ((row & 7) << 4))) = f2bf(hv);
            }
        }
        // ---- GEMM2: e2 = h @ W1, K=128, N=96 ----
        bf16x8 h0 = *(const bf16x8*)(arena + 16384 + arow * 256 + ((0   + kgrp * 16) ^ sw));
        bf16x8 h1 = *(const bf16x8*)(arena + 16384 + arow * 256 + ((64  + kgrp * 16) ^ sw));
        bf16x8 h2 = *(const bf16x8*)(arena + 16384 + arow * 256 + ((128 + kgrp * 16) ^ sw));
        bf16x8 h3 = *(const bf16x8*)(arena + 16384 + arow * 256 + ((192 + kgrp * 16) ^ sw));
        f32x4 acc2[6];
#pragma unroll
        for (int nt = 0; nt < 6; nt++) {
#pragma unroll
            for (int r = 0; r < 4; r++) acc2[nt][r] = 0.f;
        }
#pragma unroll
        for (int nt = 0; nt < 6; nt++) {
            const u16* wp = w1t + (long)(nt * 16 + (lane & 15)) * 128 + kgrp * 8;
            acc2[nt] = __builtin_amdgcn_mfma_f32_16x16x32_bf16(h0, *(const bf16x8*)(wp),      acc2[nt], 0, 0, 0);
            acc2[nt] = __builtin_amdgcn_mfma_f32_16x16x32_bf16(h1, *(const bf16x8*)(wp + 32), acc2[nt], 0, 0, 0);
            acc2[nt] = __builtin_amdgcn_mfma_f32_16x16x32_bf16(h2, *(const bf16x8*)(wp + 64), acc2[nt], 0, 0, 0);
            acc2[nt] = __builtin_amdgcn_mfma_f32_16x16x32_bf16(h3, *(const bf16x8*)(wp + 96), acc2[nt], 0, 0, 0);
        }
        // out (f32) into wave-local arena slices
#pragma unroll
        for (int nt = 0; nt < 6; nt++) {
            int col = nt * 16 + (lane & 15);
#pragma unroll
            for (int r = 0; r < 4; r++) {
                int row = mrow0 + kgrp * 4 + r;
                *(float*)(arena + outOff(row, col)) = acc2[nt][r];
            }
        }
        __syncthreads();
        // ---- run-scan reduction + one atomic per (dst-run, col); LDS reads batched by 8 ----
        if (tid < 192) {
            int half = tid / 96;
            int r0 = half * 32;
            int curd = dstS[r0];
            float m = -3.0e38f;
            for (int cc = 0; cc < 4; cc++) {
                float vv[8]; int dd[8];
#pragma unroll
                for (int rr = 0; rr < 8; rr++) {
                    int row = r0 + cc * 8 + rr;
                    vv[rr] = *(const float*)(arena + outOff(row, rcol));
                    dd[rr] = dstS[row];
                }
#pragma unroll
                for (int rr = 0; rr < 8; rr++) {
                    if (dd[rr] != curd) {
                        atomicMax(&aggKey[(size_t)curd * 96 + rcol], fkey(m + b1c));
                        curd = dd[rr]; m = vv[rr];
                    } else {
                        m = fmaxf(m, vv[rr]);
                    }
                }
            }
            atomicMax(&aggKey[(size_t)curd * 96 + rcol], fkey(m + b1c));
        }
        __syncthreads();
    }
}

// -------- K3: out = x + mlp_g(agg)  (96 -> 128 relu -> 96), MFMA, same tile layout as k_edge --------
template<int BF16>
__global__ __launch_bounds__(256)
void k_node(const void* __restrict__ x, const u32* __restrict__ aggKey,
            const u16* __restrict__ w0tg, const u16* __restrict__ w1tg,
            const void* __restrict__ gb0, const void* __restrict__ gb1,
            void* __restrict__ out, const u32* __restrict__ flags, int N)
{
    if (flags[0] != (u32)BF16) return;
    __shared__ __align__(16) char arena[32768];
    __shared__ float b0s[128];
    __shared__ float b1s[96];
    int tid = threadIdx.x;
    if (tid < 128) b0s[tid] = LD<BF16>(gb0, tid);
    if (tid < 96)  b1s[tid] = LD<BF16>(gb1, tid);
    __syncthreads();

    const int lane = tid & 63;
    const int wid  = tid >> 6;
    const int mrow0 = wid * 16;
    const int arow = mrow0 + (lane & 15);
    const int kgrp = lane >> 4;
    const int srow = tid >> 2;
    const int q = tid & 3;
    const int ssw = (srow & 7) << 4;

    float b0v[8];
#pragma unroll
    for (int nt = 0; nt < 8; nt++) b0v[nt] = b0s[nt * 16 + (lane & 15)];

    int ntile = (N + 63) / 64;
    for (int t = blockIdx.x; t < ntile; t += gridDim.x) {
        asm volatile("" ::: "memory");
        {   // stage: decode aggKey row (0 == empty -> 0.0) -> bf16 -> swizzled ein
            int n = t * 64 + srow;
            if (n < N) {
                const uint4* ar = (const uint4*)(aggKey + (size_t)n * 96) + q * 6;
#pragma unroll
                for (int j = 0; j < 3; j++) {
                    uint4 k0 = ar[2 * j], k1 = ar[2 * j + 1];
                    u32 o0 = (u32)f2bf(k0.x ? fdec(k0.x) : 0.f) | ((u32)f2bf(k0.y ? fdec(k0.y) : 0.f) << 16);
                    u32 o1 = (u32)f2bf(k0.z ? fdec(k0.z) : 0.f) | ((u32)f2bf(k0.w ? fdec(k0.w) : 0.f) << 16);
                    u32 o2 = (u32)f2bf(k1.x ? fdec(k1.x) : 0.f) | ((u32)f2bf(k1.y ? fdec(k1.y) : 0.f) << 16);
                    u32 o3 = (u32)f2bf(k1.z ? fdec(k1.z) : 0.f) | ((u32)f2bf(k1.w ? fdec(k1.w) : 0.f) << 16);
                    *(uint4*)(arena + srow * 256 + (((q * 3 + j) * 16) ^ ssw)) = make_uint4(o0, o1, o2, o3);
                }
            } else {
#pragma unroll
                for (int j = 0; j < 3; j++)
                    *(uint4*)(arena + srow * 256 + (((q * 3 + j) * 16) ^ ssw)) = make_uint4(0u, 0u, 0u, 0u);
            }
        }
        __syncthreads();
        // ---- GEMM1: h = relu(agg @ W0 + b0), K=96 ----
        int sw = (arow & 7) << 4;
        bf16x8 a0 = *(const bf16x8*)(arena + arow * 256 + ((0   + kgrp * 16) ^ sw));
        bf16x8 a1 = *(const bf16x8*)(arena + arow * 256 + ((64  + kgrp * 16) ^ sw));
        bf16x8 a2 = *(const bf16x8*)(arena + arow * 256 + ((128 + kgrp * 16) ^ sw));
        f32x4 acc[8];
#pragma unroll
        for (int nt = 0; nt < 8; nt++) {
#pragma unroll
            for (int r = 0; r < 4; r++) acc[nt][r] = 0.f;
        }
#pragma unroll
        for (int nt = 0; nt < 8; nt++) {
            const u16* wp = w0tg + (long)(nt * 16 + (lane & 15)) * 128 + kgrp * 8;
            acc[nt] = __builtin_amdgcn_mfma_f32_16x16x32_bf16(a0, *(const bf16x8*)(wp),      acc[nt], 0, 0, 0);
            acc[nt] = __builtin_amdgcn_mfma_f32_16x16x32_bf16(a1, *(const bf16x8*)(wp + 32), acc[nt], 0, 0, 0);
            acc[nt] = __builtin_amdgcn_mfma_f32_16x16x32_bf16(a2, *(const bf16x8*)(wp + 64), acc[nt], 0, 0, 0);
        }
#pragma unroll
        for (int nt = 0; nt < 8; nt++) {
            int col = nt * 16 + (lane & 15);
#pragma unroll
            for (int r = 0; r < 4; r++) {
                int row = mrow0 + kgrp * 4 + r;
                float hv = fmaxf(acc[nt][r] + b0v[nt], 0.f);
                *(u16*)(arena + 16384 + row * 256 + ((col * 2) ^ ((row & 7) << 4))) = f2bf(hv);
            }
        }
        // ---- GEMM2: e2 = h @ W1, K=128, N=96 ----
        bf16x8 h0 = *(const bf16x8*)(arena + 16384 + arow * 256 + ((0   + kgrp * 16) ^ sw));
        bf16x8 h1 = *(const bf16x8*)(arena + 16384 + arow * 256 + ((64  + kgrp * 16) ^ sw));
        bf16x8 h2 = *(const bf16x8*)(arena + 16384 + arow * 256 + ((128 + kgrp * 16) ^ sw));
        bf16x8 h3 = *(const bf16x8*)(arena + 16384 + arow * 256 + ((192 + kgrp * 16) ^ sw));
        f32x4 acc2[6];
#pragma unroll
        for (int nt = 0; nt < 6; nt++) {
#pragma unroll
            for (int r = 0; r < 4; r++) acc2[nt][r] = 0.f;
        }
#pragma unroll
        for (int nt = 0; nt < 6; nt++) {
            const u16* wp = w1tg + (long)(nt * 16 + (lane & 15)) * 128 + kgrp * 8;
            acc2[nt] = __builtin_amdgcn_mfma_f32_16x16x32_bf16(h0, *(const bf16x8*)(wp),      acc2[nt], 0, 0, 0);
            acc2[nt] = __builtin_amdgcn_mfma_f32_16x16x32_bf16(h1, *(const bf16x8*)(wp + 32), acc2[nt], 0, 0, 0);
            acc2[nt] = __builtin_amdgcn_mfma_f32_16x16x32_bf16(h2, *(const bf16x8*)(wp + 64), acc2[nt], 0, 0, 0);
            acc2[nt] = __builtin_amdgcn_mfma_f32_16x16x32_bf16(h3, *(const bf16x8*)(wp + 96), acc2[nt], 0, 0, 0);
        }
#pragma unroll
        for (int nt = 0; nt < 6; nt++) {
            int col = nt * 16 + (lane & 15);
#pragma unroll
            for (int r = 0; r < 4; r++) {
                int row = mrow0 + kgrp * 4 + r;
                *(float*)(arena + outOff(row, col)) = acc2[nt][r];
            }
        }
        __syncthreads();
        // ---- epilogue: out = x + e2 + b1, coalesced row stores ----
        {
            int n = t * 64 + srow;
            if (n < N) {
                float v[24];
#pragma unroll
                for (int c = 0; c < 24; c++) v[c] = *(const float*)(arena + outOff(srow, q * 24 + c));
                if constexpr (BF16) {
                    u16* orow = (u16*)out + (size_t)n * 96 + q * 24;
#pragma unroll
                    for (int j = 0; j < 3; j++) {
                        float xv[8];
                        unpack8((const u16*)x + (size_t)n * 96 + q * 24 + j * 8, xv);
                        u32 o[4];
#pragma unroll
                        for (int c2 = 0; c2 < 4; c2++) {
                            int c = j * 8 + 2 * c2;
                            u16 lo = f2bf(xv[2 * c2]     + v[c]     + b1s[q * 24 + c]);
                            u16 hi = f2bf(xv[2 * c2 + 1] + v[c + 1] + b1s[q * 24 + c + 1]);
                            o[c2] = (u32)lo | ((u32)hi << 16);
                        }
                        *(uint4*)(orow + j * 8) = make_uint4(o[0], o[1], o[2], o[3]);
                    }
                } else {
                    const float* xr = (const float*)x + (size_t)n * 96 + q * 24;
                    float* orow = (float*)out + (size_t)n * 96 + q * 24;
#pragma unroll
                    for (int j = 0; j < 6; j++) {
                        float4 xv = ((const float4*)xr)[j];
                        float4 o;
                        o.x = xv.x + v[4 * j + 0] + b1s[q * 24 + 4 * j + 0];
                        o.y = xv.y + v[4 * j + 1] + b1s[q * 24 + 4 * j + 1];
                        o.z = xv.z + v[4 * j + 2] + b1s[q * 24 + 4 * j + 2];
                        o.w = xv.w + v[4 * j + 3] + b1s[q * 24 + 4 * j + 3];
                        ((float4*)orow)[j] = o;
                    }
                }
            }
        }
        __syncthreads();
    }
}

extern "C" void kernel_launch(void* const* d_in, const int* in_sizes, int n_in,
                              void* d_out, int out_size, void* d_ws, size_t ws_size,
                              hipStream_t stream) {
    const void* x   = d_in[0];
    const void* pos = d_in[1];
    const void* ei  = d_in[2];
    const void* hw0 = d_in[3];
    const void* hb0 = d_in[4];
    const void* hw1 = d_in[5];
    const void* hb1 = d_in[6];
    const void* fw0 = d_in[7];
    const void* fb0 = d_in[8];
    const void* fw1 = d_in[9];
    const void* fb1 = d_in[10];
    const void* gw0 = d_in[11];
    const void* gb0 = d_in[12];
    const void* gw1 = d_in[13];
    const void* gb1 = d_in[14];

    int N  = in_sizes[0] / 96;   // 50000
    int nE = in_sizes[2] / 2;    // 800000

    // workspace layout (16B aligned), total ~26.5 MB
    u32*   flags  = (u32*)d_ws;                                 // 256 B
    float* delta  = (float*)((char*)d_ws + 256);                // 600,000 B
    u16*   w0t    = (u16*)((char*)d_ws + 600320);               // 32,768 B
    u16*   w1t    = (u16*)((char*)d_ws + 633088);               // 24,576 B
    u16*   w0tg   = (u16*)((char*)d_ws + 657664);               // 32,768 B
    u16*   w1tg   = (u16*)((char*)d_ws + 690432);               // 24,576 B
    u32*   binCur = (u32*)((char*)d_ws + 715008);               // 200,000 B (hist -> cursor)
    u32*   aggKey = (u32*)((char*)d_ws + 915072);               // 19,200,000 B
    u32*   ssrc   = (u32*)((char*)d_ws + 20115072);             // 3,200,000 B
    u32*   sdst   = (u32*)((char*)d_ws + 23315072);             // 3,200,000 B -> end 26,515,072

    k_detect<<<1, 64, 0, stream>>>((const u32*)x, (const u32*)ei, flags);
    k_init<<<1024, 256, 0, stream>>>(aggKey, N * 96);
    k_init<<<256, 256, 0, stream>>>(binCur, N);
    k_prep<<<64, 256, 0, stream>>>(fw0, fw1, w0t, w1t, flags, 3);
    k_prep<<<64, 256, 0, stream>>>(gw0, gw1, w0tg, w1tg, flags, 0);
    k_hist<<<1024, 256, 0, stream>>>((const u32*)ei, binCur, flags, nE, N);
    k_scan<<<1, 256, 0, stream>>>(binCur, N);
    k_scatter<<<1024, 256, 0, stream>>>((const u32*)ei, binCur, ssrc, sdst, flags, nE, N);
    k_delta<1><<<(N + 255) / 256, 256, 0, stream>>>(x, hw0, hb0, hw1, hb1, delta, flags, N);
    k_delta<0><<<(N + 255) / 256, 256, 0, stream>>>(x, hw0, hb0, hw1, hb1, delta, flags, N);
    k_edge<1><<<2048, 256, 0, stream>>>(x, pos, ssrc, sdst, delta, w0t, w1t, fw0, fb0, fb1, flags, aggKey, nE, N);
    k_edge<0><<<2048, 256, 0, stream>>>(x, pos, ssrc, sdst, delta, w0t, w1t, fw0, fb0, fb1, flags, aggKey, nE, N);
    int nodeGrid = (N + 63) / 64;
    k_node<1><<<nodeGrid, 256, 0, stream>>>(x, aggKey, w0tg, w1tg, gb0, gb1, d_out, flags, N);
    k_node<0><<<nodeGrid, 256, 0, stream>>>(x, aggKey, w0tg, w1tg, gb0, gb1, d_out, flags, N);
}

// Round 3
// 786.452 us; speedup vs baseline: 1.0663x; 1.0663x over previous
//
#include <hip/hip_runtime.h>
#include <hip/hip_bf16.h>

typedef unsigned short u16;
typedef unsigned int u32;
typedef __bf16 bf16x8 __attribute__((ext_vector_type(8)));
typedef float f32x4 __attribute__((ext_vector_type(4)));

__device__ __forceinline__ float bf2f(u16 h) { return __uint_as_float(((u32)h) << 16); }
__device__ __forceinline__ u16 f2bf(float f) {
    u32 u = __float_as_uint(f);
    u32 r = u + 0x7FFFu + ((u >> 16) & 1u);   // round-to-nearest-even
    return (u16)(r >> 16);
}
// monotone float->uint map for atomic max; key 0 is reserved "empty" (decodes from no writes -> 0.0)
__device__ __forceinline__ u32 fkey(float f) {
    u32 u = __float_as_uint(f);
    return ((int)u < 0) ? ~u : (u | 0x80000000u);
}
__device__ __forceinline__ float fdec(u32 k) {
    u32 u = (k & 0x80000000u) ? (k & 0x7FFFFFFFu) : ~k;
    return __uint_as_float(u);
}
__device__ __forceinline__ void unpack8(const u16* p, float* b) {
    uint4 v = *(const uint4*)p;
    b[0] = bf2f((u16)(v.x & 0xFFFF)); b[1] = bf2f((u16)(v.x >> 16));
    b[2] = bf2f((u16)(v.y & 0xFFFF)); b[3] = bf2f((u16)(v.y >> 16));
    b[4] = bf2f((u16)(v.z & 0xFFFF)); b[5] = bf2f((u16)(v.z >> 16));
    b[6] = bf2f((u16)(v.w & 0xFFFF)); b[7] = bf2f((u16)(v.w >> 16));
}
template<int BF16>
__device__ __forceinline__ float LD(const void* p, long i) {
    if constexpr (BF16) return bf2f(((const u16*)p)[i]);
    else return ((const float*)p)[i];
}

// -------- detector: flags[0]=1 if floats are bf16; flags[1]=1 if edge_index is int64 --------
__global__ void k_detect(const u32* __restrict__ x, const u32* __restrict__ ei, u32* __restrict__ flags) {
    if (threadIdx.x == 0 && blockIdx.x == 0) {
        int c = 0;
        for (int i = 0; i < 256; i++) {
            u32 e = (x[i] >> 7) & 0xFF;
            if (e >= 96 && e <= 160) c++;
        }
        flags[0] = (c >= 192) ? 1u : 0u;
        int z = 0;
        for (int i = 0; i < 64; i++) if (ei[2 * i + 1] == 0u) z++;
        flags[1] = (z >= 48) ? 1u : 0u;
    }
}

__global__ void k_init(u32* __restrict__ p, int n) {
    for (int i = blockIdx.x * blockDim.x + threadIdx.x; i < n; i += gridDim.x * blockDim.x)
        p[i] = 0u;
}

// -------- prep: transposed/padded bf16 weights.  w0t[c][kp] (128x128, kp<96 -> w0src row kp+koff),
// w1t[c][k] (96x128, pitch 128).  koff=3 for f-MLP (rel rows handled separately), 0 for g-MLP. --------
__global__ void k_prep(const void* __restrict__ w0src, const void* __restrict__ w1src,
                       u16* __restrict__ w0t, u16* __restrict__ w1t,
                       const u32* __restrict__ flags, int koff) {
    int bf = (int)flags[0];
    int tid = blockIdx.x * blockDim.x + threadIdx.x;
    int stride = gridDim.x * blockDim.x;
    for (int i = tid; i < 128 * 128; i += stride) {
        int c = i >> 7, kp = i & 127;
        float v = 0.f;
        if (kp < 96) {
            int k = kp + koff;
            v = bf ? bf2f(((const u16*)w0src)[k * 128 + c]) : ((const float*)w0src)[k * 128 + c];
        }
        w0t[(long)c * 128 + kp] = f2bf(v);
    }
    for (int i = tid; i < 96 * 128; i += stride) {
        int c = i >> 7, k = i & 127;
        float v = bf ? bf2f(((const u16*)w1src)[k * 96 + c]) : ((const float*)w1src)[k * 96 + c];
        w1t[(long)c * 128 + k] = f2bf(v);
    }
}

// -------- counting sort of edges by dst: hist -> scan -> scatter --------
__global__ void k_hist(const u32* __restrict__ ei, u32* __restrict__ hist,
                       const u32* __restrict__ flags, int nE, int N) {
    u32 i64f = flags[1];
    for (long e = blockIdx.x * blockDim.x + threadIdx.x; e < nE; e += (long)gridDim.x * blockDim.x) {
        int dst = i64f ? (int)ei[2 * ((long)nE + e)] : (int)ei[(long)nE + e];
        dst = min(max(dst, 0), N - 1);
        atomicAdd(&hist[dst], 1u);
    }
}

__global__ void k_scan(u32* __restrict__ hist, int n) {   // 1 block, 256 threads, in-place exclusive scan
    __shared__ u32 sums[256];
    __shared__ u32 offs[256];
    int tid = threadIdx.x;
    int chunk = (n + 255) / 256;
    int lo = tid * chunk, hi = min(lo + chunk, n);
    u32 s = 0;
    for (int i = lo; i < hi; i++) s += hist[i];
    sums[tid] = s;
    __syncthreads();
    if (tid == 0) {
        u32 r = 0;
        for (int i = 0; i < 256; i++) { offs[i] = r; r += sums[i]; }
    }
    __syncthreads();
    u32 r = offs[tid];
    for (int i = lo; i < hi; i++) { u32 v = hist[i]; hist[i] = r; r += v; }
}

__global__ void k_scatter(const u32* __restrict__ ei, u32* __restrict__ cur,
                          u32* __restrict__ ssrc, u32* __restrict__ sdst,
                          const u32* __restrict__ flags, int nE, int N) {
    u32 i64f = flags[1];
    for (long e = blockIdx.x * blockDim.x + threadIdx.x; e < nE; e += (long)gridDim.x * blockDim.x) {
        int src, dst;
        if (i64f) { src = (int)ei[2 * e]; dst = (int)ei[2 * ((long)nE + e)]; }
        else      { src = (int)ei[e];     dst = (int)ei[(long)nE + e]; }
        src = min(max(src, 0), N - 1);
        dst = min(max(dst, 0), N - 1);
        u32 p = atomicAdd(&cur[dst], 1u);
        ssrc[p] = (u32)src;
        sdst[p] = (u32)dst;
    }
}

// -------- K1: delta = mlp_h(x)  (96 -> 64 relu -> 3), f32 out --------
template<int BF16>
__global__ void k_delta(const void* __restrict__ x,
                        const void* __restrict__ hw0, const void* __restrict__ hb0,
                        const void* __restrict__ hw1, const void* __restrict__ hb1,
                        float* __restrict__ delta, const u32* __restrict__ flags, int N)
{
    if (flags[0] != (u32)BF16) return;
    __shared__ float w0[96 * 64];
    __shared__ float b0[64];
    __shared__ float w1[64 * 3];
    __shared__ float b1[3];
    int tid = threadIdx.x;
    for (int i = tid; i < 96 * 64; i += 256) w0[i] = LD<BF16>(hw0, i);
    if (tid < 64) b0[tid] = LD<BF16>(hb0, tid);
    if (tid < 64 * 3) w1[tid] = LD<BF16>(hw1, tid);
    if (tid < 3) b1[tid] = LD<BF16>(hb1, tid);
    __syncthreads();
    int n = blockIdx.x * 256 + tid;
    if (n >= N) return;
    float acc[64];
#pragma unroll
    for (int j = 0; j < 64; j++) acc[j] = b0[j];
    if constexpr (BF16) {
        const u32* xr = (const u32*)x + (long)n * 48;
        for (int kk = 0; kk < 48; kk++) {
            u32 p = xr[kk];
            float a0 = bf2f((u16)(p & 0xFFFF));
            float a1 = bf2f((u16)(p >> 16));
            const float* wr0 = &w0[(2 * kk) * 64];
            const float* wr1 = &w0[(2 * kk + 1) * 64];
#pragma unroll
            for (int j = 0; j < 64; j++) acc[j] += a0 * wr0[j] + a1 * wr1[j];
        }
    } else {
        const float* xr = (const float*)x + (long)n * 96;
        for (int k = 0; k < 96; k++) {
            float a0 = xr[k];
            const float* wr = &w0[k * 64];
#pragma unroll
            for (int j = 0; j < 64; j++) acc[j] += a0 * wr[j];
        }
    }
    float d0 = b1[0], d1 = b1[1], d2 = b1[2];
#pragma unroll
    for (int j = 0; j < 64; j++) {
        float h = fmaxf(acc[j], 0.f);
        d0 += h * w1[j * 3 + 0];
        d1 += h * w1[j * 3 + 1];
        d2 += h * w1[j * 3 + 2];
    }
    delta[(long)n * 3 + 0] = d0; delta[(long)n * 3 + 1] = d1; delta[(long)n * 3 + 2] = d2;
}

// -------- K2: MFMA edge MLP, BARRIER-FREE: each wave owns an independent 16-edge tile stream --------
// Per-wave LDS slice (8 KB at wid*8192):
//   ein: [16][128] bf16  (bytes 0..4096),  chunk addr = row*256 + ((c*16) ^ ((row&7)<<4))
//   h:   [16][128] bf16  (bytes 4096..8192), addr = 4096 + row*256 + ((col*2) ^ ((row&7)<<4))
//   out: [16] rows x stride 98 words, f32 (bytes 0..6272) -- overlays ein+h after fragments are in regs
// No __syncthreads in the loop: intra-wave DS ops are in-order; all producers/consumers are same-wave.
template<int BF16>
__global__ __launch_bounds__(256, 4)
void k_edge(const void* __restrict__ x, const void* __restrict__ pos,
            const u32* __restrict__ ssrc, const u32* __restrict__ sdst,
            const float* __restrict__ delta,
            const u16* __restrict__ w0t, const u16* __restrict__ w1t,
            const void* __restrict__ fw0, const void* __restrict__ fb0, const void* __restrict__ fb1,
            const u32* __restrict__ flags, u32* __restrict__ aggKey, int nE, int N)
{
    if (flags[0] != (u32)BF16) return;
    __shared__ __align__(16) char arena[32768];
    __shared__ float relS[4][64];    // [wid][row*4+c]
    __shared__ int dstS[4][16];
    __shared__ float b0s[128];
    __shared__ float b1s[96];
    __shared__ float w0rS[3 * 128];
    int tid = threadIdx.x;
    if (tid < 128) b0s[tid] = LD<BF16>(fb0, tid);
    if (tid < 96)  b1s[tid] = LD<BF16>(fb1, tid);
    for (int i = tid; i < 384; i += 256) w0rS[i] = LD<BF16>(fw0, i);   // fw0 rows 0..2 (rel part), f32
    __syncthreads();   // one-time weight/bias staging only

    const int lane = tid & 63;
    const int wid  = tid >> 6;
    char* const abase = arena + wid * 8192;        // wave-local slice
    char* const hbase = abase + 4096;
    const int r16  = lane & 15;
    const int kgrp = lane >> 4;                    // 0..3
    const int sw   = (r16 & 7) << 4;
    const int srow = lane >> 2;                    // staging row 0..15
    const int q    = lane & 3;
    const int ssw  = (srow & 7) << 4;

    float b0v[8];
#pragma unroll
    for (int nt = 0; nt < 8; nt++) b0v[nt] = b0s[nt * 16 + r16];

    const int stride = (int)gridDim.x * 4;
    const int ntile = (nE + 15) / 16;              // 50000
    int t = (int)blockIdx.x * 4 + wid;

    u32 cs = 0u, cd = 0u;
    if (t < ntile) {
        long E = min((long)t * 16 + srow, (long)nE - 1);
        cs = ssrc[E]; cd = sdst[E];
    }

    for (; t < ntile; t += stride) {
        asm volatile("" ::: "memory");   // keep B-fragment loads inside the loop (no LICM reg blowup)
        // ---- prefetch next tile's indices (breaks index->gather dep chain) ----
        u32 ns = 0u, nd = 0u;
        int tn = t + stride;
        if (tn < ntile) {
            long En = min((long)tn * 16 + srow, (long)nE - 1);
            ns = ssrc[En]; nd = sdst[En];
        }
        // ---- stage 16 edges (wave-local) ----
        {
            u32 src = cs, dst = cd;
            if (q == 3) {
                dstS[wid][srow] = (int)dst;
#pragma unroll
                for (int c = 0; c < 3; c++) {
                    relS[wid][srow * 4 + c] = LD<BF16>(pos, (long)src * 3 + c)
                                            - LD<BF16>(pos, (long)dst * 3 + c)
                                            + delta[(long)dst * 3 + c];
                }
            } else {
                if constexpr (BF16) {
                    const uint4* xp = (const uint4*)((const u16*)x + (size_t)src * 96);
#pragma unroll
                    for (int j = 0; j < 4; j++) {
                        int c = q * 4 + j;
                        *(uint4*)(abase + srow * 256 + ((c * 16) ^ ssw)) = xp[c];
                    }
                } else {
                    const float4* xp = (const float4*)((const float*)x + (size_t)src * 96);
#pragma unroll
                    for (int j = 0; j < 4; j++) {
                        int c = q * 4 + j;
                        float4 v0 = xp[2 * c], v1 = xp[2 * c + 1];
                        u32 o0 = (u32)f2bf(v0.x) | ((u32)f2bf(v0.y) << 16);
                        u32 o1 = (u32)f2bf(v0.z) | ((u32)f2bf(v0.w) << 16);
                        u32 o2 = (u32)f2bf(v1.x) | ((u32)f2bf(v1.y) << 16);
                        u32 o3 = (u32)f2bf(v1.z) | ((u32)f2bf(v1.w) << 16);
                        *(uint4*)(abase + srow * 256 + ((c * 16) ^ ssw)) = make_uint4(o0, o1, o2, o3);
                    }
                }
            }
        }
        // ---- GEMM1: h = relu(ein @ W0 + b0), K=96 MFMA + rank-3 rel init in f32 ----
        float rl[4][3];
#pragma unroll
        for (int r = 0; r < 4; r++) {
            int row = kgrp * 4 + r;
            rl[r][0] = relS[wid][row * 4 + 0];
            rl[r][1] = relS[wid][row * 4 + 1];
            rl[r][2] = relS[wid][row * 4 + 2];
        }
        f32x4 acc[8];
#pragma unroll
        for (int nt = 0; nt < 8; nt++) {
            int col = nt * 16 + r16;
            float wr0 = w0rS[col], wr1 = w0rS[128 + col], wr2 = w0rS[256 + col];
#pragma unroll
            for (int r = 0; r < 4; r++)
                acc[nt][r] = rl[r][0] * wr0 + rl[r][1] * wr1 + rl[r][2] * wr2;
        }
        bf16x8 a0 = *(const bf16x8*)(abase + r16 * 256 + ((0   + kgrp * 16) ^ sw));
        bf16x8 a1 = *(const bf16x8*)(abase + r16 * 256 + ((64  + kgrp * 16) ^ sw));
        bf16x8 a2 = *(const bf16x8*)(abase + r16 * 256 + ((128 + kgrp * 16) ^ sw));
#pragma unroll
        for (int nt = 0; nt < 8; nt++) {
            const u16* wp = w0t + (long)(nt * 16 + r16) * 128 + kgrp * 8;
            acc[nt] = __builtin_amdgcn_mfma_f32_16x16x32_bf16(a0, *(const bf16x8*)(wp),      acc[nt], 0, 0, 0);
            acc[nt] = __builtin_amdgcn_mfma_f32_16x16x32_bf16(a1, *(const bf16x8*)(wp + 32), acc[nt], 0, 0, 0);
            acc[nt] = __builtin_amdgcn_mfma_f32_16x16x32_bf16(a2, *(const bf16x8*)(wp + 64), acc[nt], 0, 0, 0);
        }
        // h -> bf16 -> wave-local LDS
#pragma unroll
        for (int nt = 0; nt < 8; nt++) {
            int col = nt * 16 + r16;
#pragma unroll
            for (int r = 0; r < 4; r++) {
                int row = kgrp * 4 + r;
                float hv = fmaxf(acc[nt][r] + b0v[nt], 0.f);
                *(u16*)(hbase + row * 256 + ((col * 2) ^ ((row & 7) << 4))) = f2bf(hv);
            }
        }
        // ---- GEMM2: e2 = h @ W1, K=128, N=96 ----
        bf16x8 h0 = *(const bf16x8*)(hbase + r16 * 256 + ((0   + kgrp * 16) ^ sw));
        bf16x8 h1 = *(const bf16x8*)(hbase + r16 * 256 + ((64  + kgrp * 16) ^ sw));
        bf16x8 h2 = *(const bf16x8*)(hbase + r16 * 256 + ((128 + kgrp * 16) ^ sw));
        bf16x8 h3 = *(const bf16x8*)(hbase + r16 * 256 + ((192 + kgrp * 16) ^ sw));
        f32x4 acc2[6];
#pragma unroll
        for (int nt = 0; nt < 6; nt++) {
#pragma unroll
            for (int r = 0; r < 4; r++) acc2[nt][r] = 0.f;
        }
#pragma unroll
        for (int nt = 0; nt < 6; nt++) {
            const u16* wp = w1t + (long)(nt * 16 + r16) * 128 + kgrp * 8;
            acc2[nt] = __builtin_amdgcn_mfma_f32_16x16x32_bf16(h0, *(const bf16x8*)(wp),      acc2[nt], 0, 0, 0);
            acc2[nt] = __builtin_amdgcn_mfma_f32_16x16x32_bf16(h1, *(const bf16x8*)(wp + 32), acc2[nt], 0, 0, 0);
            acc2[nt] = __builtin_amdgcn_mfma_f32_16x16x32_bf16(h2, *(const bf16x8*)(wp + 64), acc2[nt], 0, 0, 0);
            acc2[nt] = __builtin_amdgcn_mfma_f32_16x16x32_bf16(h3, *(const bf16x8*)(wp + 96), acc2[nt], 0, 0, 0);
        }
        // out (f32) -> wave-local overlay, stride 98 words (2-way banks on write & read = free)
#pragma unroll
        for (int nt = 0; nt < 6; nt++) {
            int col = nt * 16 + r16;
#pragma unroll
            for (int r = 0; r < 4; r++) {
                int row = kgrp * 4 + r;
                *(float*)(abase + (row * 98 + col) * 4) = acc2[nt][r];
            }
        }
        // ---- run-scan reduction + one atomic per (dst-run, col), wave-local ----
#pragma unroll
        for (int p = 0; p < 2; p++) {
            int col = p * 64 + lane;
            if (p == 0 || lane < 32) {
                float b1c = b1s[col];
                int curd = dstS[wid][0];
                float m = -3.0e38f;
#pragma unroll
                for (int row = 0; row < 16; row++) {
                    float v = *(const float*)(abase + (row * 98 + col) * 4);
                    int d = dstS[wid][row];
                    if (d != curd) {
                        atomicMax(&aggKey[(size_t)curd * 96 + col], fkey(m + b1c));
                        curd = d; m = v;
                    } else {
                        m = fmaxf(m, v);
                    }
                }
                atomicMax(&aggKey[(size_t)curd * 96 + col], fkey(m + b1c));
            }
        }
        cs = ns; cd = nd;
    }
}

// -------- K3: out = x + mlp_g(agg)  (96 -> 128 relu -> 96), MFMA, 64-node tiles --------
template<int BF16>
__global__ __launch_bounds__(256)
void k_node(const void* __restrict__ x, const u32* __restrict__ aggKey,
            const u16* __restrict__ w0tg, const u16* __restrict__ w1tg,
            const void* __restrict__ gb0, const void* __restrict__ gb1,
            void* __restrict__ out, const u32* __restrict__ flags, int N)
{
    if (flags[0] != (u32)BF16) return;
    __shared__ __align__(16) char arena[32768];
    __shared__ float b0s[128];
    __shared__ float b1s[96];
    int tid = threadIdx.x;
    if (tid < 128) b0s[tid] = LD<BF16>(gb0, tid);
    if (tid < 96)  b1s[tid] = LD<BF16>(gb1, tid);
    __syncthreads();

    const int lane = tid & 63;
    const int wid  = tid >> 6;
    const int mrow0 = wid * 16;
    const int arow = mrow0 + (lane & 15);
    const int kgrp = lane >> 4;
    const int srow = tid >> 2;
    const int q = tid & 3;
    const int ssw = (srow & 7) << 4;

    float b0v[8];
#pragma unroll
    for (int nt = 0; nt < 8; nt++) b0v[nt] = b0s[nt * 16 + (lane & 15)];

    auto outOff = [](int row, int col) {
        int j = row & 15, w2 = row >> 4;
        int base = (j < 8) ? (w2 * 4096 + j * 512) : (16384 + w2 * 4096 + (j - 8) * 512);
        return base + ((col ^ (((row >> 2) & 3) << 4)) << 2);
    };

    int ntile = (N + 63) / 64;
    for (int t = blockIdx.x; t < ntile; t += gridDim.x) {
        asm volatile("" ::: "memory");
        {   // stage: decode aggKey row (0 == empty -> 0.0) -> bf16 -> swizzled ein
            int n = t * 64 + srow;
            if (n < N) {
                const uint4* ar = (const uint4*)(aggKey + (size_t)n * 96) + q * 6;
#pragma unroll
                for (int j = 0; j < 3; j++) {
                    uint4 k0 = ar[2 * j], k1 = ar[2 * j + 1];
                    u32 o0 = (u32)f2bf(k0.x ? fdec(k0.x) : 0.f) | ((u32)f2bf(k0.y ? fdec(k0.y) : 0.f) << 16);
                    u32 o1 = (u32)f2bf(k0.z ? fdec(k0.z) : 0.f) | ((u32)f2bf(k0.w ? fdec(k0.w) : 0.f) << 16);
                    u32 o2 = (u32)f2bf(k1.x ? fdec(k1.x) : 0.f) | ((u32)f2bf(k1.y ? fdec(k1.y) : 0.f) << 16);
                    u32 o3 = (u32)f2bf(k1.z ? fdec(k1.z) : 0.f) | ((u32)f2bf(k1.w ? fdec(k1.w) : 0.f) << 16);
                    *(uint4*)(arena + srow * 256 + (((q * 3 + j) * 16) ^ ssw)) = make_uint4(o0, o1, o2, o3);
                }
            } else {
#pragma unroll
                for (int j = 0; j < 3; j++)
                    *(uint4*)(arena + srow * 256 + (((q * 3 + j) * 16) ^ ssw)) = make_uint4(0u, 0u, 0u, 0u);
            }
        }
        __syncthreads();
        // ---- GEMM1: h = relu(agg @ W0 + b0), K=96 ----
        int sw = (arow & 7) << 4;
        bf16x8 a0 = *(const bf16x8*)(arena + arow * 256 + ((0   + kgrp * 16) ^ sw));
        bf16x8 a1 = *(const bf16x8*)(arena + arow * 256 + ((64  + kgrp * 16) ^ sw));
        bf16x8 a2 = *(const bf16x8*)(arena + arow * 256 + ((128 + kgrp * 16) ^ sw));
        f32x4 acc[8];
#pragma unroll
        for (int nt = 0; nt < 8; nt++) {
#pragma unroll
            for (int r = 0; r < 4; r++) acc[nt][r] = 0.f;
        }
#pragma unroll
        for (int nt = 0; nt < 8; nt++) {
            const u16* wp = w0tg + (long)(nt * 16 + (lane & 15)) * 128 + kgrp * 8;
            acc[nt] = __builtin_amdgcn_mfma_f32_16x16x32_bf16(a0, *(const bf16x8*)(wp),      acc[nt], 0, 0, 0);
            acc[nt] = __builtin_amdgcn_mfma_f32_16x16x32_bf16(a1, *(const bf16x8*)(wp + 32), acc[nt], 0, 0, 0);
            acc[nt] = __builtin_amdgcn_mfma_f32_16x16x32_bf16(a2, *(const bf16x8*)(wp + 64), acc[nt], 0, 0, 0);
        }
#pragma unroll
        for (int nt = 0; nt < 8; nt++) {
            int col = nt * 16 + (lane & 15);
#pragma unroll
            for (int r = 0; r < 4; r++) {
                int row = mrow0 + kgrp * 4 + r;
                float hv = fmaxf(acc[nt][r] + b0v[nt], 0.f);
                *(u16*)(arena + 16384 + row * 256 + ((col * 2) ^ ((row & 7) << 4))) = f2bf(hv);
            }
        }
        // ---- GEMM2: e2 = h @ W1, K=128, N=96 ----
        bf16x8 h0 = *(const bf16x8*)(arena + 16384 + arow * 256 + ((0   + kgrp * 16) ^ sw));
        bf16x8 h1 = *(const bf16x8*)(arena + 16384 + arow * 256 + ((64  + kgrp * 16) ^ sw));
        bf16x8 h2 = *(const bf16x8*)(arena + 16384 + arow * 256 + ((128 + kgrp * 16) ^ sw));
        bf16x8 h3 = *(const bf16x8*)(arena + 16384 + arow * 256 + ((192 + kgrp * 16) ^ sw));
        f32x4 acc2[6];
#pragma unroll
        for (int nt = 0; nt < 6; nt++) {
#pragma unroll
            for (int r = 0; r < 4; r++) acc2[nt][r] = 0.f;
        }
#pragma unroll
        for (int nt = 0; nt < 6; nt++) {
            const u16* wp = w1tg + (long)(nt * 16 + (lane & 15)) * 128 + kgrp * 8;
            acc2[nt] = __builtin_amdgcn_mfma_f32_16x16x32_bf16(h0, *(const bf16x8*)(wp),      acc2[nt], 0, 0, 0);
            acc2[nt] = __builtin_amdgcn_mfma_f32_16x16x32_bf16(h1, *(const bf16x8*)(wp + 32), acc2[nt], 0, 0, 0);
            acc2[nt] = __builtin_amdgcn_mfma_f32_16x16x32_bf16(h2, *(const bf16x8*)(wp + 64), acc2[nt], 0, 0, 0);
            acc2[nt] = __builtin_amdgcn_mfma_f32_16x16x32_bf16(h3, *(const bf16x8*)(wp + 96), acc2[nt], 0, 0, 0);
        }
#pragma unroll
        for (int nt = 0; nt < 6; nt++) {
            int col = nt * 16 + (lane & 15);
#pragma unroll
            for (int r = 0; r < 4; r++) {
                int row = mrow0 + kgrp * 4 + r;
                *(float*)(arena + outOff(row, col)) = acc2[nt][r];
            }
        }
        __syncthreads();
        // ---- epilogue: out = x + e2 + b1, coalesced row stores ----
        {
            int n = t * 64 + srow;
            if (n < N) {
                float v[24];
#pragma unroll
                for (int c = 0; c < 24; c++) v[c] = *(const float*)(arena + outOff(srow, q * 24 + c));
                if constexpr (BF16) {
                    u16* orow = (u16*)out + (size_t)n * 96 + q * 24;
#pragma unroll
                    for (int j = 0; j < 3; j++) {
                        float xv[8];
                        unpack8((const u16*)x + (size_t)n * 96 + q * 24 + j * 8, xv);
                        u32 o[4];
#pragma unroll
                        for (int c2 = 0; c2 < 4; c2++) {
                            int c = j * 8 + 2 * c2;
                            u16 lo = f2bf(xv[2 * c2]     + v[c]     + b1s[q * 24 + c]);
                            u16 hi = f2bf(xv[2 * c2 + 1] + v[c + 1] + b1s[q * 24 + c + 1]);
                            o[c2] = (u32)lo | ((u32)hi << 16);
                        }
                        *(uint4*)(orow + j * 8) = make_uint4(o[0], o[1], o[2], o[3]);
                    }
                } else {
                    const float* xr = (const float*)x + (size_t)n * 96 + q * 24;
                    float* orow = (float*)out + (size_t)n * 96 + q * 24;
#pragma unroll
                    for (int j = 0; j < 6; j++) {
                        float4 xv = ((const float4*)xr)[j];
                        float4 o;
                        o.x = xv.x + v[4 * j + 0] + b1s[q * 24 + 4 * j + 0];
                        o.y = xv.y + v[4 * j + 1] + b1s[q * 24 + 4 * j + 1];
                        o.z = xv.z + v[4 * j + 2] + b1s[q * 24 + 4 * j + 2];
                        o.w = xv.w + v[4 * j + 3] + b1s[q * 24 + 4 * j + 3];
                        ((float4*)orow)[j] = o;
                    }
                }
            }
        }
        __syncthreads();
    }
}

extern "C" void kernel_launch(void* const* d_in, const int* in_sizes, int n_in,
                              void* d_out, int out_size, void* d_ws, size_t ws_size,
                              hipStream_t stream) {
    const void* x   = d_in[0];
    const void* pos = d_in[1];
    const void* ei  = d_in[2];
    const void* hw0 = d_in[3];
    const void* hb0 = d_in[4];
    const void* hw1 = d_in[5];
    const void* hb1 = d_in[6];
    const void* fw0 = d_in[7];
    const void* fb0 = d_in[8];
    const void* fw1 = d_in[9];
    const void* fb1 = d_in[10];
    const void* gw0 = d_in[11];
    const void* gb0 = d_in[12];
    const void* gw1 = d_in[13];
    const void* gb1 = d_in[14];

    int N  = in_sizes[0] / 96;   // 50000
    int nE = in_sizes[2] / 2;    // 800000

    // workspace layout (16B aligned), total ~26.5 MB
    u32*   flags  = (u32*)d_ws;                                 // 256 B
    float* delta  = (float*)((char*)d_ws + 256);                // 600,000 B
    u16*   w0t    = (u16*)((char*)d_ws + 600320);               // 32,768 B
    u16*   w1t    = (u16*)((char*)d_ws + 633088);               // 24,576 B
    u16*   w0tg   = (u16*)((char*)d_ws + 657664);               // 32,768 B
    u16*   w1tg   = (u16*)((char*)d_ws + 690432);               // 24,576 B
    u32*   binCur = (u32*)((char*)d_ws + 715008);               // 200,000 B (hist -> cursor)
    u32*   aggKey = (u32*)((char*)d_ws + 915072);               // 19,200,000 B
    u32*   ssrc   = (u32*)((char*)d_ws + 20115072);             // 3,200,000 B
    u32*   sdst   = (u32*)((char*)d_ws + 23315072);             // 3,200,000 B -> end 26,515,072

    k_detect<<<1, 64, 0, stream>>>((const u32*)x, (const u32*)ei, flags);
    k_init<<<1024, 256, 0, stream>>>(aggKey, N * 96);
    k_init<<<256, 256, 0, stream>>>(binCur, N);
    k_prep<<<64, 256, 0, stream>>>(fw0, fw1, w0t, w1t, flags, 3);
    k_prep<<<64, 256, 0, stream>>>(gw0, gw1, w0tg, w1tg, flags, 0);
    k_hist<<<1024, 256, 0, stream>>>((const u32*)ei, binCur, flags, nE, N);
    k_scan<<<1, 256, 0, stream>>>(binCur, N);
    k_scatter<<<1024, 256, 0, stream>>>((const u32*)ei, binCur, ssrc, sdst, flags, nE, N);
    k_delta<1><<<(N + 255) / 256, 256, 0, stream>>>(x, hw0, hb0, hw1, hb1, delta, flags, N);
    k_delta<0><<<(N + 255) / 256, 256, 0, stream>>>(x, hw0, hb0, hw1, hb1, delta, flags, N);
    k_edge<1><<<2048, 256, 0, stream>>>(x, pos, ssrc, sdst, delta, w0t, w1t, fw0, fb0, fb1, flags, aggKey, nE, N);
    k_edge<0><<<2048, 256, 0, stream>>>(x, pos, ssrc, sdst, delta, w0t, w1t, fw0, fb0, fb1, flags, aggKey, nE, N);
    int nodeGrid = (N + 63) / 64;
    k_node<1><<<nodeGrid, 256, 0, stream>>>(x, aggKey, w0tg, w1tg, gb0, gb1, d_out, flags, N);
    k_node<0><<<nodeGrid, 256, 0, stream>>>(x, aggKey, w0tg, w1tg, gb0, gb1, d_out, flags, N);
}